// Round 15
// baseline (132.754 us; speedup 1.0000x reference)
//
#include <hip/hip_runtime.h>

// LDS forward collapsed to causal conv:
//   y[b,t,o] = sum_{d<=t} x[b,t-d] * K[d,o] + G[t,o]
//   K[d,o] = sum_s C[s,o] A[s]^d B[s]  (+ M[o,0,d-1] for d in 1..5)
//   G[t,o] = sum_s C[s,o] A[s]^{t+1} h0[s]
//
// R15: halve LDS reads/MFMA. Wave = 128t x 32o (mi=8, ni=2): the Toeplitz
// window's 2 refills/k-step now feed 16 MFMAs (0.125 reads/MFMA vs 0.25 in
// R5-R13). Block = 4 waves (256 thr) = 512t x 32o, NB=8, grid (16 oc, 32 bg)
// = 512 blocks = 2/CU (independent barriers -> phase-slide + T5 setprio).
// B-slice in regs (128 VGPR), G reloaded from L2 per batch (VMEM has slack),
// staging via global_load_lds + counted vmcnt(16) barrier.

typedef __attribute__((ext_vector_type(8))) short short8v;
typedef __attribute__((ext_vector_type(4))) float float4v;

#define NB 8

static __device__ __forceinline__ unsigned short f2bf(float f) {
    union { float f; unsigned int u; } x; x.f = f;
    unsigned int r = x.u + 0x7fffu + ((x.u >> 16) & 1u);  // RNE
    return (unsigned short)(r >> 16);
}

// ---------------- prep: KT/G (blocks 0..1023) + XOCT (blocks 1024..1279) ---
__global__ __launch_bounds__(256) void k_prep(const float* __restrict__ A,
                                              const float* __restrict__ B,
                                              const float* __restrict__ h0,
                                              const float* __restrict__ C,
                                              const float* __restrict__ M,
                                              const float* __restrict__ x,
                                              unsigned short* __restrict__ KT,
                                              float* __restrict__ G,
                                              short8v* __restrict__ XOCT) {
    __shared__ float PBL[512][4];
    __shared__ float PHL[512][4];
    __shared__ float red[4][64][8];
    __shared__ unsigned short xs[512];
    const int tid = threadIdx.x;

    if (blockIdx.x < 1024) {
        const int d0 = (blockIdx.x & 127) * 4;
        const int oc = blockIdx.x >> 7;

        #pragma unroll
        for (int q = 0; q < 2; ++q) {
            int ss = tid + q * 256;
            float a = A[ss];
            float r = 1.0f, base = a;
            #pragma unroll
            for (int bit = 0; bit < 9; ++bit) {
                if (d0 & (1 << bit)) r *= base;
                base *= base;
            }
            float bs = B[ss], hs = h0[ss];
            #pragma unroll
            for (int j = 0; j < 4; ++j) {
                PBL[ss][j] = r * bs;
                PHL[ss][j] = r * a * hs;
                r *= a;
            }
        }
        __syncthreads();

        const int lane = tid & 63;
        const int sc   = tid >> 6;
        const int o    = oc * 64 + lane;
        float kt[4] = {0.f, 0.f, 0.f, 0.f};
        float gg[4] = {0.f, 0.f, 0.f, 0.f};
        for (int si = 0; si < 128; si += 8) {
            float c8[8];
            #pragma unroll
            for (int u = 0; u < 8; ++u)
                c8[u] = C[(sc * 128 + si + u) * 512 + o];
            #pragma unroll
            for (int u = 0; u < 8; ++u) {
                int s = sc * 128 + si + u;
                #pragma unroll
                for (int j = 0; j < 4; ++j) {
                    kt[j] = fmaf(PBL[s][j], c8[u], kt[j]);
                    gg[j] = fmaf(PHL[s][j], c8[u], gg[j]);
                }
            }
        }
        #pragma unroll
        for (int j = 0; j < 4; ++j) {
            red[sc][lane][j]     = kt[j];
            red[sc][lane][j + 4] = gg[j];
        }
        __syncthreads();
        if (sc == 0) {
            #pragma unroll
            for (int j = 0; j < 4; ++j) {
                float v  = red[0][lane][j] + red[1][lane][j]
                         + red[2][lane][j] + red[3][lane][j];
                float gv = red[0][lane][j+4] + red[1][lane][j+4]
                         + red[2][lane][j+4] + red[3][lane][j+4];
                int d = d0 + j;
                if (d >= 1 && d <= 5) v += M[o * 5 + (d - 1)];
                KT[o * 512 + d] = f2bf(v);
                G[d * 512 + o]  = gv;
            }
        }
    } else {
        // xprep: unpadded reversed-octet table, 1024 entries per batch
        const int b = blockIdx.x - 1024;
        #pragma unroll
        for (int q = 0; q < 2; ++q) {
            int i = tid * 2 + q;
            xs[i] = f2bf(x[b * 512 + 511 - i]);
        }
        __syncthreads();
        short8v* dst = XOCT + (size_t)b * 1024;
        #pragma unroll
        for (int q = 0; q < 4; ++q) {
            int e = tid * 4 + q;
            short8v v;
            #pragma unroll
            for (int jj = 0; jj < 8; ++jj) {
                int i = e + jj;
                v[jj] = (i < 512) ? (short)xs[i] : (short)0;
            }
            dst[e] = v;
        }
    }
}

// ---------------- main: 512 blocks x 256 thr, wave = 128t x 32o ------------
__global__ __launch_bounds__(256, 2) void k_main(const short8v* __restrict__ XOCT,
                                                 const unsigned short* __restrict__ KT,
                                                 const float* __restrict__ G,
                                                 float* __restrict__ out) {
    __shared__ short8v xbuf[2][1024];   // 32 KB, double-buffered octet tables

    const int bo0 = blockIdx.x * 32;    // 16 o-chunks
    const int b0  = blockIdx.y * NB;    // 32 batch-groups
    const int tid  = threadIdx.x;
    const int lane = tid & 63;
    const int wv   = tid >> 6;          // 0..3 -> 128t chunk
    const int t0w  = wv * 128;
    const int lrow = lane & 15;
    const int g    = lane >> 4;

    // ---- prologue: stage batch 0 + B-slice regs ----
    {
        const short8v* src = XOCT + (size_t)b0 * 1024;
        #pragma unroll
        for (int q = 0; q < 4; ++q) {
            int base = q * 256 + wv * 64;
            __builtin_amdgcn_global_load_lds(
                (const __attribute__((address_space(1))) void*)(src + base + lane),
                (__attribute__((address_space(3))) void*)(&xbuf[0][base]),
                16, 0, 0);
        }
    }

    short8v bfr[2][16];                 // wave's 32o x 512k B slice (128 VGPR)
    #pragma unroll
    for (int ni = 0; ni < 2; ++ni) {
        const unsigned short* bp = KT + (bo0 + ni * 16 + lrow) * 512 + g * 8;
        #pragma unroll
        for (int ks = 0; ks < 16; ++ks)
            bfr[ni][ks] = *(const short8v*)(bp + ks * 32);
    }

    asm volatile("s_waitcnt vmcnt(0)" ::: "memory");
    __builtin_amdgcn_s_barrier();

    const int E0 = 511 - t0w - lrow + 8 * g;   // frag j at xbuf[p][E0 + 16j]

    int p = 0;
    for (int bi = 0; bi < NB; ++bi) {
        // stage next batch early (oldest in vmcnt order)
        if (bi + 1 < NB) {
            const short8v* src = XOCT + (size_t)(b0 + bi + 1) * 1024;
            short8v* dstb = xbuf[p ^ 1];
            #pragma unroll
            for (int q = 0; q < 4; ++q) {
                int base = q * 256 + wv * 64;
                __builtin_amdgcn_global_load_lds(
                    (const __attribute__((address_space(1))) void*)(src + base + lane),
                    (__attribute__((address_space(3))) void*)(dstb + base),
                    16, 0, 0);
            }
        }

        const short8v* xo = xbuf[p];

        float4v acc[8][2];
        #pragma unroll
        for (int mi = 0; mi < 8; ++mi)
            #pragma unroll
            for (int ni = 0; ni < 2; ++ni)
                acc[mi][ni] = (float4v)(0.0f);

        // A window: 8 frags j = 2ks-7 .. 2ks, 2 refills per k-step
        short8v aw[8];
        #pragma unroll
        for (int j = -7; j <= 0; ++j)
            aw[j & 7] = xo[E0 + 16 * j];

        __builtin_amdgcn_s_setprio(1);
        #pragma unroll
        for (int ks = 0; ks < 16; ++ks) {
            // consume oldest slots first (mi=7,6), then refill them for ks+1
            #pragma unroll
            for (int mi = 7; mi >= 6; --mi) {
                acc[mi][0] = __builtin_amdgcn_mfma_f32_16x16x32_bf16(
                    bfr[0][ks], aw[(2 * ks - mi) & 7], acc[mi][0], 0, 0, 0);
                acc[mi][1] = __builtin_amdgcn_mfma_f32_16x16x32_bf16(
                    bfr[1][ks], aw[(2 * ks - mi) & 7], acc[mi][1], 0, 0, 0);
            }
            if (ks < 15) {
                aw[(2 * ks + 1) & 7] = xo[E0 + 16 * (2 * ks + 1)];
                aw[(2 * ks + 2) & 7] = xo[E0 + 16 * (2 * ks + 2)];
            }
            #pragma unroll
            for (int mi = 5; mi >= 0; --mi) {
                acc[mi][0] = __builtin_amdgcn_mfma_f32_16x16x32_bf16(
                    bfr[0][ks], aw[(2 * ks - mi) & 7], acc[mi][0], 0, 0, 0);
                acc[mi][1] = __builtin_amdgcn_mfma_f32_16x16x32_bf16(
                    bfr[1][ks], aw[(2 * ks - mi) & 7], acc[mi][1], 0, 0, 0);
            }
        }
        __builtin_amdgcn_s_setprio(0);

        // epilogue: G from L2 (batch-invariant data, cache-hot) + stores
        float* op = out + (size_t)(b0 + bi) * 262144;
        #pragma unroll
        for (int mi = 0; mi < 8; ++mi) {
            const int t = t0w + mi * 16 + lrow;
            const float* gp = G + t * 512 + bo0 + g * 4;
            float4v gv0 = *(const float4v*)(gp);
            float4v gv1 = *(const float4v*)(gp + 16);
            float* rp = op + t * 512 + bo0 + g * 4;
            *(float4v*)(rp)      = acc[mi][0] + gv0;
            *(float4v*)(rp + 16) = acc[mi][1] + gv1;
        }

        // counted barrier: drains only the 4 stage-glds (oldest); the 16
        // epilogue stores stay in flight under the next MFMA loop.
        if (bi + 1 < NB) {
            asm volatile("s_waitcnt vmcnt(16)" ::: "memory");
            __builtin_amdgcn_s_barrier();
            p ^= 1;
        }
    }
}

extern "C" void kernel_launch(void* const* d_in, const int* in_sizes, int n_in,
                              void* d_out, int out_size, void* d_ws, size_t ws_size,
                              hipStream_t stream) {
    const float* x  = (const float*)d_in[0];   // [256,512,1]
    const float* A  = (const float*)d_in[1];   // [512]
    const float* B  = (const float*)d_in[2];   // [1,512]
    const float* C  = (const float*)d_in[3];   // [512,512]
    const float* M  = (const float*)d_in[4];   // [512,1,5]
    const float* h0 = (const float*)d_in[5];   // [512]
    float* out = (float*)d_out;

    char* ws = (char*)d_ws;
    unsigned short* KT   = (unsigned short*)ws;                      // 512 KB
    float*          G    = (float*)(ws + (1u << 19));                // 1 MB
    short8v*        XOCT = (short8v*)(ws + (1u << 19) + (1u << 20)); // 4 MB

    k_prep<<<1280, 256, 0, stream>>>(A, B, h0, C, M, x, KT, G, XOCT);
    k_main<<<dim3(16, 32), 256, 0, stream>>>(XOCT, KT, G, out);
}